// Round 5
// baseline (32.354 us; speedup 1.0000x reference)
//
#include <hip/hip_runtime.h>

// out[b,k] = tanh( sum_{m in segment k} x[b,m] * w[m] ),  seg_ids sorted.
//
// R5: single fused kernel. Each block = (b, 64 consecutive segments).
//  - Phase 0: per-lane binary search on seg_ids gives the 64 segment starts;
//    one extra wave-uniform search (scalarizes to s_loads) gives the end.
//    seg_ids is 256 KB -> L2-resident; searches hide under other waves' x streams.
//  - Phase 1: float4-coalesced load of x*w for the block's contiguous m-range
//    into LDS (exact-range guarded).
//  - Phase 2: thread t reduces segment k0+t from LDS with ds_read_b128 +
//    per-element cndmask (no scalar loop), writes tanh.
// One dispatch, no atomics, x read exactly once.

#define TPB 64                // threads per block == segments per block
#define CH  1280              // LDS floats: 5 KB; range is Poisson(1024), +8 sigma
#define VPT (CH / TPB / 4)    // float4 loads per thread per chunk = 5

__global__ __launch_bounds__(TPB) void fused_seg_reduce_tanh(
        const float* __restrict__ x,
        const float* __restrict__ w,
        const int* __restrict__ seg_ids,
        float* __restrict__ out,
        int M, int K) {
    __shared__ __align__(16) float prod[CH];
    __shared__ int sp[TPB + 1];

    const int t  = threadIdx.x;
    const int k0 = blockIdx.x * TPB;
    const int b  = blockIdx.y;
    const float* __restrict__ xb = x + (size_t)b * (size_t)M;

    // ---- phase 0: segment boundaries via binary search ----
    {
        int tgt = k0 + t;                 // lower_bound(seg_ids, tgt)
        int lo = 0, hi = M;
        while (lo < hi) {
            int mid = (lo + hi) >> 1;
            bool lt = seg_ids[mid] < tgt;
            lo = lt ? mid + 1 : lo;
            hi = lt ? hi : mid;
        }
        sp[t] = lo;
        int tgt2 = k0 + TPB;              // wave-uniform -> scalar loads
        int lo2 = 0, hi2 = M;
        while (lo2 < hi2) {
            int mid = (lo2 + hi2) >> 1;
            bool lt = seg_ids[mid] < tgt2;
            lo2 = lt ? mid + 1 : lo2;
            hi2 = lt ? hi2 : mid;
        }
        sp[TPB] = lo2;                    // all lanes write same value
    }
    __syncthreads();                      // 1-wave block: waitcnt only

    const int s    = sp[0];               // block-uniform range [s, e)
    const int e    = sp[TPB];
    const int base = s & ~3;              // 16B-aligned window start
    const int a_t  = sp[t];               // this thread's segment [a_t, b_t)
    const int b_t  = sp[t + 1];

    float sum = 0.0f;
    for (int c = base; c < e; c += CH) {  // single trip in practice
        const float4* __restrict__ x4 = reinterpret_cast<const float4*>(xb + c);
        const float4* __restrict__ w4 = reinterpret_cast<const float4*>(w + c);
        float4* __restrict__ p4 = reinterpret_cast<float4*>(prod);
        // ---- phase 1: cooperative float4 load + multiply into LDS ----
        #pragma unroll
        for (int j = 0; j < VPT; ++j) {
            int idx = t + j * TPB;        // float4 index within chunk
            int mm  = c + idx * 4;        // float index (4-aligned)
            float4 v = make_float4(0.f, 0.f, 0.f, 0.f);
            if (mm < e) {                 // mm 4-aligned & < e <= M -> safe 16B
                float4 xv = x4[idx];
                float4 wv = w4[idx];
                v.x = xv.x * wv.x; v.y = xv.y * wv.y;
                v.z = xv.z * wv.z; v.w = xv.w * wv.w;
            }
            p4[idx] = v;                  // ds_write_b128, conflict-free
        }
        __syncthreads();
        // ---- phase 2: vectorized LDS reduce of own segment ----
        int lo = max(a_t, c) - c;         // relative [lo, hi) within chunk
        int hi = min(b_t, c + CH) - c;
        int r0 = lo & ~3;                 // aligned vec start
        for (int r = r0; r < hi; r += 4) {
            float4 v = *reinterpret_cast<const float4*>(&prod[r]);
            sum += (r + 0 >= lo && r + 0 < hi) ? v.x : 0.0f;
            sum += (r + 1 >= lo && r + 1 < hi) ? v.y : 0.0f;
            sum += (r + 2 >= lo && r + 2 < hi) ? v.z : 0.0f;
            sum += (r + 3 >= lo && r + 3 < hi) ? v.w : 0.0f;
        }
        __syncthreads();
    }
    out[(size_t)b * (size_t)K + k0 + t] = tanhf(sum);
}

extern "C" void kernel_launch(void* const* d_in, const int* in_sizes, int n_in,
                              void* d_out, int out_size, void* d_ws, size_t ws_size,
                              hipStream_t stream) {
    const float* x       = (const float*)d_in[0];
    const float* w       = (const float*)d_in[1];
    const int*   seg_ids = (const int*)d_in[2];
    float* out = (float*)d_out;

    const int M = in_sizes[1];           // 65536 (w length)
    const int B = in_sizes[0] / M;       // 256
    const int K = out_size / B;          // 4096

    dim3 grid(K / TPB, B);               // (64, 256) = 16384 blocks
    fused_seg_reduce_tanh<<<grid, TPB, 0, stream>>>(x, w, seg_ids, out, M, K);
}

// Round 6
// 27.021 us; speedup vs baseline: 1.1973x; 1.1973x over previous
//
#include <hip/hip_runtime.h>

// out[b,k] = tanh( sum_{m in segment k} x[b,m] * w[m] ),  seg_ids sorted.
//
// R6: one fused kernel. Block = (4 batches) x (64 consecutive segments).
//  - Phase 0: lanes 0..64 binary-search seg_ids for the 65 boundaries,
//    publish via LDS. ONE __syncthreads; amortized over 4 batches.
//  - Phase 1: wave wv stages x[b0+wv]*w for the contiguous m-range into its
//    PRIVATE LDS quarter (float4, exact-range guarded). No cross-wave deps.
//  - Phase 2: thread reduces its segment from LDS (float4 + cndmask), tanh,
//    coalesced store. Waves free-run; zero barriers after phase 0.
// Rationale (R5 counters): latency/MLP-bound (HBM 12%, VALU 22%, occ 50%).
// 4-wave blocks beat the ~16 WG/CU cap; b-batching quadruples per-block MLP
// and amortizes the boundary search.

#define SEGB 64               // segments per block
#define NB   4                // batches per block
#define TPB  (SEGB * NB)      // 256 threads = 4 waves
#define CH   1280             // floats per wave chunk (mean 1024 + 8 sigma)
#define VPT  (CH / 64 / 4)    // float4 loads per lane per chunk = 5

__global__ __launch_bounds__(TPB) void fused_seg_reduce_tanh(
        const float* __restrict__ x,
        const float* __restrict__ w,
        const int* __restrict__ seg_ids,
        float* __restrict__ out,
        int M, int K) {
    __shared__ __align__(16) float prod[NB][CH];
    __shared__ int sp[SEGB + 1];

    const int t   = threadIdx.x;
    const int ln  = t & 63;               // lane within wave
    const int wv  = t >> 6;               // wave id = batch offset
    const int k0  = blockIdx.x * SEGB;
    const int b   = blockIdx.y * NB + wv;
    const float* __restrict__ xb = x + (size_t)b * (size_t)M;

    // ---- phase 0: 65 boundaries via binary search (threads 0..64) ----
    if (t <= SEGB) {
        int tgt = k0 + t;                 // lower_bound(seg_ids, tgt)
        int lo = 0, hi = M;
        while (lo < hi) {
            int mid = (lo + hi) >> 1;
            bool lt = seg_ids[mid] < tgt;
            lo = lt ? mid + 1 : lo;
            hi = lt ? hi : mid;
        }
        sp[t] = lo;
    }
    __syncthreads();                      // publish sp; last barrier in kernel

    const int s    = sp[0];               // block-uniform range [s, e)
    const int e    = sp[SEGB];
    const int base = s & ~3;              // 16B-aligned window start
    const int a_t  = sp[ln];              // this lane's segment [a_t, b_t)
    const int b_t  = sp[ln + 1];

    float sum = 0.0f;
    for (int c = base; c < e; c += CH) {  // single trip in practice
        const float4* __restrict__ x4 = reinterpret_cast<const float4*>(xb + c);
        const float4* __restrict__ w4 = reinterpret_cast<const float4*>(w + c);
        float4* __restrict__ p4 = reinterpret_cast<float4*>(prod[wv]);
        // ---- phase 1: per-wave float4 stage of x*w into private quarter ----
        #pragma unroll
        for (int j = 0; j < VPT; ++j) {
            int idx = ln + j * 64;        // float4 index within chunk
            int mm  = c + idx * 4;        // float index (4-aligned)
            float4 v = make_float4(0.f, 0.f, 0.f, 0.f);
            if (mm < e) {                 // mm 4-aligned & < e <= M -> safe 16B
                float4 xv = x4[idx];
                float4 wv4 = w4[idx];
                v.x = xv.x * wv4.x; v.y = xv.y * wv4.y;
                v.z = xv.z * wv4.z; v.w = xv.w * wv4.w;
            }
            p4[idx] = v;                  // ds_write_b128, conflict-free
        }
        // same-wave RAW through LDS -> compiler emits lgkmcnt wait; no barrier
        // ---- phase 2: vectorized LDS reduce of own segment ----
        int lo = max(a_t, c) - c;         // relative [lo, hi) within chunk
        int hi = min(b_t, c + CH) - c;
        int r0 = lo & ~3;
        for (int r = r0; r < hi; r += 4) {
            float4 v = *reinterpret_cast<const float4*>(&prod[wv][r]);
            sum += (r + 0 >= lo) ? v.x : 0.0f;          // r+i < hi handled below
            sum += (r + 1 >= lo && r + 1 < hi) ? v.y : 0.0f;
            sum += (r + 2 >= lo && r + 2 < hi) ? v.z : 0.0f;
            sum += (r + 3 >= lo && r + 3 < hi) ? v.w : 0.0f;
        }
    }
    out[(size_t)b * (size_t)K + k0 + ln] = tanhf(sum);
}

extern "C" void kernel_launch(void* const* d_in, const int* in_sizes, int n_in,
                              void* d_out, int out_size, void* d_ws, size_t ws_size,
                              hipStream_t stream) {
    const float* x       = (const float*)d_in[0];
    const float* w       = (const float*)d_in[1];
    const int*   seg_ids = (const int*)d_in[2];
    float* out = (float*)d_out;

    const int M = in_sizes[1];           // 65536 (w length)
    const int B = in_sizes[0] / M;       // 256
    const int K = out_size / B;          // 4096

    dim3 grid(K / SEGB, B / NB);         // (64, 64) = 4096 blocks
    fused_seg_reduce_tanh<<<grid, TPB, 0, stream>>>(x, w, seg_ids, out, M, K);
}